// Round 5
// baseline (285.338 us; speedup 1.0000x reference)
//
#include <hip/hip_runtime.h>
#include <math.h>

typedef _Float16 v8h __attribute__((ext_vector_type(8)));
typedef float v4f __attribute__((ext_vector_type(4)));

#define UNITS    50
#define K3       150
#define FDIM     64
#define TSTEPS   128
#define BATCH    4096
#define NB       8      // batch rows per block (MFMA M rows 8..15 duplicate 0..7)
#define H16S     72     // halves per h row (50 h + slot50=1.0 + pad); 144 B stride
#define H32S     52

#if __has_builtin(__builtin_amdgcn_exp2f)
__device__ __forceinline__ float fast_exp2(float x) { return __builtin_amdgcn_exp2f(x); }
#else
__device__ __forceinline__ float fast_exp2(float x) { return exp2f(x); }
#endif
#if __has_builtin(__builtin_amdgcn_rcpf)
__device__ __forceinline__ float fast_rcp(float x) { return __builtin_amdgcn_rcpf(x); }
#else
__device__ __forceinline__ float fast_rcp(float x) { return 1.0f / x; }
#endif

// 4 waves per block (wave nt owns u-columns nt*16..+15, all 3 gates ->
// register-local gate math). NB=8: half-wasted MFMA M, but grid=512 gives
// 2 blocks/CU -> 2 independent waves per SIMD to hide the per-step latency
// chain (ds_read -> MFMA chain -> exp2 chain -> ds_write -> barrier).
__global__ __launch_bounds__(256, 2)
void gru_2b(const float* __restrict__ x, const float* __restrict__ W,
            const float* __restrict__ U, const float* __restrict__ bv,
            const float* __restrict__ Wd, const float* __restrict__ bd,
            float* __restrict__ out) {
    __shared__ _Float16 hs16[2][NB * H16S];   // ping-pong h state (f16)
    __shared__ float    hs32[NB * H32S];      // epilogue only

    const int tid  = threadIdx.x;
    const int nt   = tid >> 6;          // wave id = ntile (wave-uniform)
    const int lane = tid & 63;
    const int n    = lane & 15;
    const int nr   = n & 7;             // valid batch row (rows 8..15 duplicate)
    const int quad = lane >> 4;
    const int b0   = blockIdx.x * NB;
    const int c    = nt * 16 + n;       // this lane's unit column

    // ---- init both h buffers: zeros, constant 1.0 at slot u=50 (bias-fold row) ----
    for (int i = tid; i < NB * H16S; i += 256) {
        _Float16 v = ((i % H16S) == 50) ? (_Float16)1.f : (_Float16)0.f;
        hs16[0][i] = v;
        hs16[1][i] = v;
    }

    // ---- B fragments for this wave's ntile (VGPR-resident whole kernel) ----
    // combined K rows: 0..63 = W, 64..113 = U, 114 = b[1] h-col fold, rest 0
    v8h Bz[4], Br[4], Bh[4];
    #pragma unroll
    for (int kt = 0; kt < 4; ++kt) {
        v8h fz, fr, fh;
        #pragma unroll
        for (int j = 0; j < 8; ++j) {
            const int k = kt * 32 + quad * 8 + j;
            float vz = 0.f, vr = 0.f, vh = 0.f;
            if (c < UNITS) {
                if (k < FDIM) {
                    vz = W[k * K3 + c];
                    vr = W[k * K3 + 50 + c];
                    vh = W[k * K3 + 100 + c];
                } else if (k < FDIM + UNITS) {
                    const int ur = k - FDIM;
                    vz = U[ur * K3 + c];
                    vr = U[ur * K3 + 50 + c];
                    vh = U[ur * K3 + 100 + c];
                } else if (k == FDIM + UNITS) {
                    vh = bv[250 + c];           // b[1] h-col via h-slot u=50 == 1.0
                }
            }
            fz[j] = (_Float16)vz; fr[j] = (_Float16)vr; fh[j] = (_Float16)vh;
        }
        Bz[kt] = fz; Br[kt] = fr; Bh[kt] = fh;
    }

    // ---- sigmoid-folded bias constants for this lane's column ----
    const float CE = -1.44269504f;      // sigmoid(a) = 1 / (1 + 2^(CE*a))
    float bzc = 0.f, brc = 0.f, bx = 0.f;
    if (c < UNITS) {
        bzc = CE * (bv[c]      + bv[150 + c]);
        brc = CE * (bv[50 + c] + bv[200 + c]);
        bx  = bv[100 + c];
    }

    // f32 h state in registers: h32[r] = h[m=quad*4+r][u=c] (quads 2,3 duplicate)
    v4f h32 = {0.f, 0.f, 0.f, 0.f};

    // ---- x prefetch for t=0 (lane covers batch row b0+nr, k=quad*8..+7, +32) ----
    const float* xbase = x + ((size_t)(b0 + nr) * TSTEPS) * FDIM + quad * 8;
    v4f px0 = *(const v4f*)(xbase + 0);
    v4f px1 = *(const v4f*)(xbase + 4);
    v4f px2 = *(const v4f*)(xbase + 32);
    v4f px3 = *(const v4f*)(xbase + 36);

    __syncthreads();

    for (int t = 0; t < TSTEPS; ++t) {
        const _Float16* hrd = hs16[t & 1];
        _Float16*       hwr = hs16[(t + 1) & 1];

        // A fragments: x part from regs, h part from LDS (row nr)
        v8h A0, A1;
        #pragma unroll
        for (int j = 0; j < 4; ++j) {
            A0[j]     = (_Float16)px0[j];
            A0[j + 4] = (_Float16)px1[j];
            A1[j]     = (_Float16)px2[j];
            A1[j + 4] = (_Float16)px3[j];
        }
        v8h A2 = *(const v8h*)(&hrd[nr * H16S + quad * 8]);       // k 64..95  (h 0..31)
        v8h A3 = *(const v8h*)(&hrd[nr * H16S + 32 + quad * 8]);  // k 96..127 (h 32..49, 1.0, 0s)

        if (t + 1 < TSTEPS) {
            const float* xp = xbase + (size_t)(t + 1) * FDIM;
            px0 = *(const v4f*)(xp + 0);
            px1 = *(const v4f*)(xp + 4);
            px2 = *(const v4f*)(xp + 32);
            px3 = *(const v4f*)(xp + 36);
        }

        const v4f zero4 = {0.f, 0.f, 0.f, 0.f};
        // x-dependent MFMAs first (ready from regs), h-dependent after
        v4f ax = {bx, bx, bx, bx};
        v4f az = __builtin_amdgcn_mfma_f32_16x16x32_f16(A0, Bz[0], zero4, 0, 0, 0);
        az     = __builtin_amdgcn_mfma_f32_16x16x32_f16(A1, Bz[1], az,    0, 0, 0);
        v4f ar = __builtin_amdgcn_mfma_f32_16x16x32_f16(A0, Br[0], zero4, 0, 0, 0);
        ar     = __builtin_amdgcn_mfma_f32_16x16x32_f16(A1, Br[1], ar,    0, 0, 0);
        ax     = __builtin_amdgcn_mfma_f32_16x16x32_f16(A0, Bh[0], ax,    0, 0, 0);
        ax     = __builtin_amdgcn_mfma_f32_16x16x32_f16(A1, Bh[1], ax,    0, 0, 0);
        az     = __builtin_amdgcn_mfma_f32_16x16x32_f16(A2, Bz[2], az,    0, 0, 0);
        az     = __builtin_amdgcn_mfma_f32_16x16x32_f16(A3, Bz[3], az,    0, 0, 0);
        ar     = __builtin_amdgcn_mfma_f32_16x16x32_f16(A2, Br[2], ar,    0, 0, 0);
        ar     = __builtin_amdgcn_mfma_f32_16x16x32_f16(A3, Br[3], ar,    0, 0, 0);
        v4f ah = __builtin_amdgcn_mfma_f32_16x16x32_f16(A2, Bh[2], zero4, 0, 0, 0);
        ah     = __builtin_amdgcn_mfma_f32_16x16x32_f16(A3, Bh[3], ah,    0, 0, 0);

        // register-local gate math: 4 rows (m = quad*4 + r; quads 2,3 duplicate)
        #pragma unroll
        for (int r = 0; r < 4; ++r) {
            const float ez = fast_exp2(fmaf(az[r], CE, bzc));
            const float er = fast_exp2(fmaf(ar[r], CE, brc));
            const float pz = 1.f + ez;
            const float pr = 1.f + er;
            const float d  = fast_rcp(pz * pr);
            const float zg = d * pr;                 // sigmoid(z-pre)
            const float rg = d * pz;                 // sigmoid(r-pre)
            const float hc = fmaxf(fmaf(rg, ah[r], ax[r]), 0.f);  // ah includes b[1]
            const float hn = fmaf(zg, h32[r] - hc, hc);           // z*h + (1-z)*hc
            h32[r] = hn;
            if (quad < 2 && c < UNITS)
                hwr[(quad * 4 + r) * H16S + c] = (_Float16)hn;
        }
        __syncthreads();   // orders h writes (t+1 buf) vs next step's reads
    }

    // ---- epilogue: out[b] = h_T @ Wd + bd (exact f32 h) ----
    if (quad < 2 && c < UNITS) {
        #pragma unroll
        for (int r = 0; r < 4; ++r)
            hs32[(quad * 4 + r) * H32S + c] = h32[r];
    }
    __syncthreads();
    if (tid < NB) {
        float acc = bd[0];
        #pragma unroll
        for (int u = 0; u < UNITS; ++u)
            acc = fmaf(hs32[tid * H32S + u], Wd[u], acc);
        out[b0 + tid] = acc;
    }
}

extern "C" void kernel_launch(void* const* d_in, const int* in_sizes, int n_in,
                              void* d_out, int out_size, void* d_ws, size_t ws_size,
                              hipStream_t stream) {
    const float* x    = (const float*)d_in[0];
    const float* W    = (const float*)d_in[1];
    const float* U    = (const float*)d_in[2];
    const float* bv   = (const float*)d_in[3];
    const float* Wd   = (const float*)d_in[4];
    const float* bd   = (const float*)d_in[5];
    float* out = (float*)d_out;

    dim3 grid(BATCH / NB);    // 512 blocks -> 2 per CU
    dim3 block(256);          // 4 waves
    gru_2b<<<grid, block, 0, stream>>>(x, W, U, bv, Wd, bd, out);
}

// Round 6
// 277.714 us; speedup vs baseline: 1.0275x; 1.0275x over previous
//
#include <hip/hip_runtime.h>
#include <math.h>

typedef _Float16 v8h __attribute__((ext_vector_type(8)));
typedef float v4f __attribute__((ext_vector_type(4)));

#define UNITS    50
#define K3       150
#define FDIM     64
#define TSTEPS   128
#define BATCH    4096
#define NB       16     // batch rows per block (MFMA M)
#define H16S     72     // halves per h row (50 h + slot50=1.0 + pad); 144 B stride
#define H32S     52

#if __has_builtin(__builtin_amdgcn_exp2f)
__device__ __forceinline__ float fast_exp2(float x) { return __builtin_amdgcn_exp2f(x); }
#else
__device__ __forceinline__ float fast_exp2(float x) { return exp2f(x); }
#endif
#if __has_builtin(__builtin_amdgcn_rcpf)
__device__ __forceinline__ float fast_rcp(float x) { return __builtin_amdgcn_rcpf(x); }
#else
__device__ __forceinline__ float fast_rcp(float x) { return 1.0f / x; }
#endif

// CK-style barrier: orders LDS traffic (this wave's ds reads AND writes are
// drained by lgkmcnt(0)) but does NOT drain vmcnt -> the x global prefetch
// stays in flight across the barrier instead of paying L3/HBM latency
// (~600-900 cyc) inside every timestep like __syncthreads() does.
__device__ __forceinline__ void sync_lds() {
    asm volatile("s_waitcnt lgkmcnt(0)" ::: "memory");
    __builtin_amdgcn_s_barrier();
}

// 4 waves per block, one 16-batch tile per block (1 block/CU). Wave nt owns
// u-columns nt*16..+15, all 3 gates -> Z/R/HX/HH stay lane- and register-
// aligned (C layout row=quad*4+reg, col=lane&15); gate math register-local.
// z/r split into x-part (computed while the h ds_read is in flight) and
// h-part (2-deep MFMA chain) to shorten the per-step critical path.
__global__ __launch_bounds__(256, 1)
void gru_nodrain(const float* __restrict__ x, const float* __restrict__ W,
                 const float* __restrict__ U, const float* __restrict__ bv,
                 const float* __restrict__ Wd, const float* __restrict__ bd,
                 float* __restrict__ out) {
    __shared__ _Float16 hs16[2][NB * H16S];   // ping-pong h state (f16)
    __shared__ float    hs32[NB * H32S];      // epilogue only

    const int tid  = threadIdx.x;
    const int nt   = tid >> 6;          // wave id = ntile (wave-uniform)
    const int lane = tid & 63;
    const int n    = lane & 15;
    const int quad = lane >> 4;
    const int b0   = blockIdx.x * NB;
    const int c    = nt * 16 + n;       // this lane's unit column

    // ---- init both h buffers: zeros, constant 1.0 at slot u=50 (bias-fold row) ----
    for (int i = tid; i < NB * H16S; i += 256) {
        _Float16 v = ((i % H16S) == 50) ? (_Float16)1.f : (_Float16)0.f;
        hs16[0][i] = v;
        hs16[1][i] = v;
    }

    // ---- B fragments for this wave's ntile (VGPR-resident whole kernel) ----
    // combined K rows: 0..63 = W, 64..113 = U, 114 = b[1] h-col fold, rest 0
    v8h Bz[4], Br[4], Bh[4];
    #pragma unroll
    for (int kt = 0; kt < 4; ++kt) {
        v8h fz, fr, fh;
        #pragma unroll
        for (int j = 0; j < 8; ++j) {
            const int k = kt * 32 + quad * 8 + j;
            float vz = 0.f, vr = 0.f, vh = 0.f;
            if (c < UNITS) {
                if (k < FDIM) {
                    vz = W[k * K3 + c];
                    vr = W[k * K3 + 50 + c];
                    vh = W[k * K3 + 100 + c];
                } else if (k < FDIM + UNITS) {
                    const int ur = k - FDIM;
                    vz = U[ur * K3 + c];
                    vr = U[ur * K3 + 50 + c];
                    vh = U[ur * K3 + 100 + c];
                } else if (k == FDIM + UNITS) {
                    vh = bv[250 + c];           // b[1] h-col via h-slot u=50 == 1.0
                }
            }
            fz[j] = (_Float16)vz; fr[j] = (_Float16)vr; fh[j] = (_Float16)vh;
        }
        Bz[kt] = fz; Br[kt] = fr; Bh[kt] = fh;
    }

    // ---- sigmoid-folded bias constants for this lane's column ----
    const float CE = -1.44269504f;      // sigmoid(a) = 1 / (1 + 2^(CE*a))
    float bzc = 0.f, brc = 0.f, bx = 0.f;
    if (c < UNITS) {
        bzc = CE * (bv[c]      + bv[150 + c]);
        brc = CE * (bv[50 + c] + bv[200 + c]);
        bx  = bv[100 + c];
    }

    // f32 h state in registers: h32[r] = h[m=quad*4+r][u=c]
    v4f h32 = {0.f, 0.f, 0.f, 0.f};

    // ---- 2-deep x prefetch (lane covers batch row b0+n, k=quad*8..+7, +32) ----
    const float* xbase = x + ((size_t)(b0 + n) * TSTEPS) * FDIM + quad * 8;
    v4f px[2][4];
    #pragma unroll
    for (int s = 0; s < 2; ++s) {
        const float* xp = xbase + (size_t)s * FDIM;
        px[s][0] = *(const v4f*)(xp + 0);
        px[s][1] = *(const v4f*)(xp + 4);
        px[s][2] = *(const v4f*)(xp + 32);
        px[s][3] = *(const v4f*)(xp + 36);
    }

    __syncthreads();

    #pragma unroll 2
    for (int t = 0; t < TSTEPS; ++t) {
        const int pb = t & 1;
        const _Float16* hrd = hs16[t & 1];
        _Float16*       hwr = hs16[(t + 1) & 1];

        // A fragments: x part from prefetch regs (issue h ds_reads first)
        v8h A2 = *(const v8h*)(&hrd[n * H16S + quad * 8]);       // k 64..95  (h 0..31)
        v8h A3 = *(const v8h*)(&hrd[n * H16S + 32 + quad * 8]);  // k 96..127 (h 32..49, 1.0, 0s)
        v8h A0, A1;
        #pragma unroll
        for (int j = 0; j < 4; ++j) {
            A0[j]     = (_Float16)px[pb][0][j];
            A0[j + 4] = (_Float16)px[pb][1][j];
            A1[j]     = (_Float16)px[pb][2][j];
            A1[j + 4] = (_Float16)px[pb][3][j];
        }

        // refill the just-consumed buffer with step t+2 (stays in flight
        // across the non-draining barrier; consumed 2 steps from now)
        if (t + 2 < TSTEPS) {
            const float* xp = xbase + (size_t)(t + 2) * FDIM;
            px[pb][0] = *(const v4f*)(xp + 0);
            px[pb][1] = *(const v4f*)(xp + 4);
            px[pb][2] = *(const v4f*)(xp + 32);
            px[pb][3] = *(const v4f*)(xp + 36);
        }

        const v4f zero4 = {0.f, 0.f, 0.f, 0.f};
        // x-parts: independent of the h ds_read, issue during its latency
        v4f axx = {bx, bx, bx, bx};
        v4f azx = __builtin_amdgcn_mfma_f32_16x16x32_f16(A0, Bz[0], zero4, 0, 0, 0);
        azx     = __builtin_amdgcn_mfma_f32_16x16x32_f16(A1, Bz[1], azx,   0, 0, 0);
        v4f arx = __builtin_amdgcn_mfma_f32_16x16x32_f16(A0, Br[0], zero4, 0, 0, 0);
        arx     = __builtin_amdgcn_mfma_f32_16x16x32_f16(A1, Br[1], arx,   0, 0, 0);
        axx     = __builtin_amdgcn_mfma_f32_16x16x32_f16(A0, Bh[0], axx,   0, 0, 0);
        axx     = __builtin_amdgcn_mfma_f32_16x16x32_f16(A1, Bh[1], axx,   0, 0, 0);
        // h-parts: 2-deep chains after A2/A3 arrive
        v4f azh = __builtin_amdgcn_mfma_f32_16x16x32_f16(A2, Bz[2], zero4, 0, 0, 0);
        azh     = __builtin_amdgcn_mfma_f32_16x16x32_f16(A3, Bz[3], azh,   0, 0, 0);
        v4f arh = __builtin_amdgcn_mfma_f32_16x16x32_f16(A2, Br[2], zero4, 0, 0, 0);
        arh     = __builtin_amdgcn_mfma_f32_16x16x32_f16(A3, Br[3], arh,   0, 0, 0);
        v4f ahh = __builtin_amdgcn_mfma_f32_16x16x32_f16(A2, Bh[2], zero4, 0, 0, 0);
        ahh     = __builtin_amdgcn_mfma_f32_16x16x32_f16(A3, Bh[3], ahh,   0, 0, 0);

        // register-local gate math: 4 rows (m = quad*4 + r)
        #pragma unroll
        for (int r = 0; r < 4; ++r) {
            const float az = azx[r] + azh[r];
            const float ar = arx[r] + arh[r];
            const float ez = fast_exp2(fmaf(az, CE, bzc));
            const float er = fast_exp2(fmaf(ar, CE, brc));
            const float pz = 1.f + ez;
            const float pr = 1.f + er;
            const float d  = fast_rcp(pz * pr);
            const float zg = d * pr;                 // sigmoid(z-pre)
            const float rg = d * pz;                 // sigmoid(r-pre)
            const float hc = fmaxf(fmaf(rg, ahh[r], axx[r]), 0.f);  // ahh incl b[1]
            const float hn = fmaf(zg, h32[r] - hc, hc);             // z*h + (1-z)*hc
            h32[r] = hn;
            if (c < UNITS)
                hwr[(quad * 4 + r) * H16S + c] = (_Float16)hn;
        }
        sync_lds();   // LDS-ordered barrier; x prefetch stays in flight
    }

    // ---- epilogue: out[b] = h_T @ Wd + bd (exact f32 h) ----
    if (c < UNITS) {
        #pragma unroll
        for (int r = 0; r < 4; ++r)
            hs32[(quad * 4 + r) * H32S + c] = h32[r];
    }
    __syncthreads();
    if (tid < NB) {
        float acc = bd[0];
        #pragma unroll
        for (int u = 0; u < UNITS; ++u)
            acc = fmaf(hs32[tid * H32S + u], Wd[u], acc);
        out[b0 + tid] = acc;
    }
}

extern "C" void kernel_launch(void* const* d_in, const int* in_sizes, int n_in,
                              void* d_out, int out_size, void* d_ws, size_t ws_size,
                              hipStream_t stream) {
    const float* x    = (const float*)d_in[0];
    const float* W    = (const float*)d_in[1];
    const float* U    = (const float*)d_in[2];
    const float* bv   = (const float*)d_in[3];
    const float* Wd   = (const float*)d_in[4];
    const float* bd   = (const float*)d_in[5];
    float* out = (float*)d_out;

    dim3 grid(BATCH / NB);    // 256 blocks -> 1 per CU
    dim3 block(256);          // 4 waves, one per SIMD
    gru_nodrain<<<grid, block, 0, stream>>>(x, W, U, bv, Wd, bd, out);
}

// Round 7
// 277.658 us; speedup vs baseline: 1.0277x; 1.0002x over previous
//
#include <hip/hip_runtime.h>
#include <math.h>

typedef _Float16 v8h __attribute__((ext_vector_type(8)));
typedef float v4f __attribute__((ext_vector_type(4)));

#define UNITS    50
#define K3       150
#define FDIM     64
#define TSTEPS   128
#define BATCH    4096
#define NB       16     // batch rows per block (MFMA M)
#define H16S     72     // halves per h row (50 h + slot50=1.0 + pad); 144 B stride
#define H32S     52

#if __has_builtin(__builtin_amdgcn_exp2f)
__device__ __forceinline__ float fast_exp2(float x) { return __builtin_amdgcn_exp2f(x); }
#else
__device__ __forceinline__ float fast_exp2(float x) { return exp2f(x); }
#endif
#if __has_builtin(__builtin_amdgcn_rcpf)
__device__ __forceinline__ float fast_rcp(float x) { return __builtin_amdgcn_rcpf(x); }
#else
__device__ __forceinline__ float fast_rcp(float x) { return 1.0f / x; }
#endif

// LDS-only barrier: orders this wave's ds reads/writes (lgkmcnt) without
// draining vmcnt, so the deep x global prefetch stays in flight.
__device__ __forceinline__ void sync_lds() {
    asm volatile("s_waitcnt lgkmcnt(0)" ::: "memory");
    __builtin_amdgcn_s_barrier();
}

// 4 waves/block, one 16-batch tile/block (1 block/CU). Wave nt owns u-columns
// nt*16..+15, all 3 gates (Z/R/HX/HH lane- and register-aligned).
// Key change vs prior rounds: xp = x@W is computed 4 steps AHEAD into a
// register ring (xz/xr/xh) by 6 refill-MFMAs that are independent of h and
// fill the h-chain's stall slots. The serial h-critical path per step is just:
// ds_read h -> ONE MFMA (xp folded in as C operand) + parallel partner + add
// -> gate math -> ds_write -> lgkm barrier.
__global__ __launch_bounds__(256, 1)
void gru_ring(const float* __restrict__ x, const float* __restrict__ W,
              const float* __restrict__ U, const float* __restrict__ bv,
              const float* __restrict__ Wd, const float* __restrict__ bd,
              float* __restrict__ out) {
    __shared__ _Float16 hs16[2][NB * H16S];   // ping-pong h state (f16)
    __shared__ float    hs32[NB * H32S];      // epilogue only

    const int tid  = threadIdx.x;
    const int nt   = tid >> 6;          // wave id = ntile (wave-uniform)
    const int lane = tid & 63;
    const int n    = lane & 15;
    const int quad = lane >> 4;
    const int b0   = blockIdx.x * NB;
    const int c    = nt * 16 + n;       // this lane's unit column

    // ---- init both h buffers: zeros, constant 1.0 at slot u=50 (bias-fold row) ----
    for (int i = tid; i < NB * H16S; i += 256) {
        _Float16 v = ((i % H16S) == 50) ? (_Float16)1.f : (_Float16)0.f;
        hs16[0][i] = v;
        hs16[1][i] = v;
    }

    // ---- B fragments for this wave's ntile (VGPR-resident whole kernel) ----
    // combined K rows: 0..63 = W, 64..113 = U, 114 = b[1] h-col fold, rest 0
    v8h Bz[4], Br[4], Bh[4];
    #pragma unroll
    for (int kt = 0; kt < 4; ++kt) {
        v8h fz, fr, fh;
        #pragma unroll
        for (int j = 0; j < 8; ++j) {
            const int k = kt * 32 + quad * 8 + j;
            float vz = 0.f, vr = 0.f, vh = 0.f;
            if (c < UNITS) {
                if (k < FDIM) {
                    vz = W[k * K3 + c];
                    vr = W[k * K3 + 50 + c];
                    vh = W[k * K3 + 100 + c];
                } else if (k < FDIM + UNITS) {
                    const int ur = k - FDIM;
                    vz = U[ur * K3 + c];
                    vr = U[ur * K3 + 50 + c];
                    vh = U[ur * K3 + 100 + c];
                } else if (k == FDIM + UNITS) {
                    vh = bv[250 + c];           // b[1] h-col via h-slot u=50 == 1.0
                }
            }
            fz[j] = (_Float16)vz; fr[j] = (_Float16)vr; fh[j] = (_Float16)vh;
        }
        Bz[kt] = fz; Br[kt] = fr; Bh[kt] = fh;
    }

    // ---- sigmoid-folded bias constants for this lane's column ----
    const float CE = -1.44269504f;      // sigmoid(a) = 1 / (1 + 2^(CE*a))
    float bzc = 0.f, brc = 0.f, bx = 0.f;
    if (c < UNITS) {
        bzc = CE * (bv[c]      + bv[150 + c]);
        brc = CE * (bv[50 + c] + bv[200 + c]);
        bx  = bv[100 + c];
    }

    // f32 h state in registers: h32[r] = h[m=quad*4+r][u=c]
    v4f h32 = {0.f, 0.f, 0.f, 0.f};

    const float* xbase = x + ((size_t)(b0 + n) * TSTEPS) * FDIM + quad * 8;
    const v4f z4 = {0.f, 0.f, 0.f, 0.f};
    const v4f ch = {bx, bx, bx, bx};

    // ---- xp register ring: xz/xr/xh[s] hold x_t@W (+b0 for h gate) for t = s (mod 4) ----
    v4f xz[4], xr[4], xh[4];
    #pragma unroll
    for (int s = 0; s < 4; ++s) {
        const float* xp = xbase + (size_t)s * FDIM;
        v4f p0 = *(const v4f*)(xp + 0);
        v4f p1 = *(const v4f*)(xp + 4);
        v4f p2 = *(const v4f*)(xp + 32);
        v4f p3 = *(const v4f*)(xp + 36);
        v8h A0, A1;
        #pragma unroll
        for (int j = 0; j < 4; ++j) {
            A0[j]     = (_Float16)p0[j];
            A0[j + 4] = (_Float16)p1[j];
            A1[j]     = (_Float16)p2[j];
            A1[j + 4] = (_Float16)p3[j];
        }
        v4f tz = __builtin_amdgcn_mfma_f32_16x16x32_f16(A0, Bz[0], z4, 0, 0, 0);
        tz     = __builtin_amdgcn_mfma_f32_16x16x32_f16(A1, Bz[1], tz, 0, 0, 0);
        v4f tr = __builtin_amdgcn_mfma_f32_16x16x32_f16(A0, Br[0], z4, 0, 0, 0);
        tr     = __builtin_amdgcn_mfma_f32_16x16x32_f16(A1, Br[1], tr, 0, 0, 0);
        v4f th = __builtin_amdgcn_mfma_f32_16x16x32_f16(A0, Bh[0], ch, 0, 0, 0);
        th     = __builtin_amdgcn_mfma_f32_16x16x32_f16(A1, Bh[1], th, 0, 0, 0);
        xz[s] = tz; xr[s] = tr; xh[s] = th;
    }

    // ---- px ring (x raw values, consumed to refill xp ring 4 steps ahead) ----
    v4f px[2][4];
    #pragma unroll
    for (int s = 0; s < 2; ++s) {
        const float* xp = xbase + (size_t)(4 + s) * FDIM;
        px[s][0] = *(const v4f*)(xp + 0);
        px[s][1] = *(const v4f*)(xp + 4);
        px[s][2] = *(const v4f*)(xp + 32);
        px[s][3] = *(const v4f*)(xp + 36);
    }

    __syncthreads();

    #pragma unroll 4
    for (int t = 0; t < TSTEPS; ++t) {
        const int s  = t & 3;
        const int pp = t & 1;
        const _Float16* hrd = hs16[t & 1];
        _Float16*       hwr = hs16[(t + 1) & 1];

        // serial-path LDS reads first
        v8h A2 = *(const v8h*)(&hrd[n * H16S + quad * 8]);       // h 0..31
        v8h A3 = *(const v8h*)(&hrd[n * H16S + 32 + quad * 8]);  // h 32..49, 1.0, 0s

        // pack refill A frags (for t+4) from px, then reload px with x_{t+6}
        const bool do_refill = (t + 4 < TSTEPS);
        v8h N0, N1;
        if (do_refill) {
            #pragma unroll
            for (int j = 0; j < 4; ++j) {
                N0[j]     = (_Float16)px[pp][0][j];
                N0[j + 4] = (_Float16)px[pp][1][j];
                N1[j]     = (_Float16)px[pp][2][j];
                N1[j + 4] = (_Float16)px[pp][3][j];
            }
        }
        if (t + 6 < TSTEPS) {
            const float* xp = xbase + (size_t)(t + 6) * FDIM;
            px[pp][0] = *(const v4f*)(xp + 0);
            px[pp][1] = *(const v4f*)(xp + 4);
            px[pp][2] = *(const v4f*)(xp + 32);
            px[pp][3] = *(const v4f*)(xp + 36);
        }

        // h-dependent MFMAs: 1-deep chains, xp folded in as C where possible
        v4f azA = __builtin_amdgcn_mfma_f32_16x16x32_f16(A2, Bz[2], xz[s], 0, 0, 0);
        v4f azB = __builtin_amdgcn_mfma_f32_16x16x32_f16(A3, Bz[3], z4,    0, 0, 0);
        v4f arA = __builtin_amdgcn_mfma_f32_16x16x32_f16(A2, Br[2], xr[s], 0, 0, 0);
        v4f arB = __builtin_amdgcn_mfma_f32_16x16x32_f16(A3, Br[3], z4,    0, 0, 0);
        v4f ahA = __builtin_amdgcn_mfma_f32_16x16x32_f16(A2, Bh[2], z4,    0, 0, 0);
        v4f ahB = __builtin_amdgcn_mfma_f32_16x16x32_f16(A3, Bh[3], z4,    0, 0, 0);
        const v4f hx = xh[s];

        // refill MFMAs for t+4: independent of h -> issue in the stall slots
        if (do_refill) {
            v4f tz = __builtin_amdgcn_mfma_f32_16x16x32_f16(N0, Bz[0], z4, 0, 0, 0);
            tz     = __builtin_amdgcn_mfma_f32_16x16x32_f16(N1, Bz[1], tz, 0, 0, 0);
            v4f tr = __builtin_amdgcn_mfma_f32_16x16x32_f16(N0, Br[0], z4, 0, 0, 0);
            tr     = __builtin_amdgcn_mfma_f32_16x16x32_f16(N1, Br[1], tr, 0, 0, 0);
            v4f th = __builtin_amdgcn_mfma_f32_16x16x32_f16(N0, Bh[0], ch, 0, 0, 0);
            th     = __builtin_amdgcn_mfma_f32_16x16x32_f16(N1, Bh[1], th, 0, 0, 0);
            xz[s] = tz; xr[s] = tr; xh[s] = th;
        }

        // register-local gate math: 4 rows (m = quad*4 + r)
        #pragma unroll
        for (int r = 0; r < 4; ++r) {
            const float az = azA[r] + azB[r];
            const float ar = arA[r] + arB[r];
            const float hh = ahA[r] + ahB[r];      // includes b[1] via slot-50 fold
            const float ez = fast_exp2(fmaf(az, CE, bzc));
            const float er = fast_exp2(fmaf(ar, CE, brc));
            const float pz = 1.f + ez;
            const float pr = 1.f + er;
            const float d  = fast_rcp(pz * pr);
            const float zg = d * pr;               // sigmoid(z-pre)
            const float rg = d * pz;               // sigmoid(r-pre)
            const float hc = fmaxf(fmaf(rg, hh, hx[r]), 0.f);
            const float hn = fmaf(zg, h32[r] - hc, hc);   // z*h + (1-z)*hc
            h32[r] = hn;
            if (c < UNITS)
                hwr[(quad * 4 + r) * H16S + c] = (_Float16)hn;
        }
        sync_lds();   // LDS-ordered barrier; global prefetch stays in flight
    }

    // ---- epilogue: out[b] = h_T @ Wd + bd (exact f32 h) ----
    if (c < UNITS) {
        #pragma unroll
        for (int r = 0; r < 4; ++r)
            hs32[(quad * 4 + r) * H32S + c] = h32[r];
    }
    __syncthreads();
    if (tid < NB) {
        float acc = bd[0];
        #pragma unroll
        for (int u = 0; u < UNITS; ++u)
            acc = fmaf(hs32[tid * H32S + u], Wd[u], acc);
        out[b0 + tid] = acc;
    }
}

extern "C" void kernel_launch(void* const* d_in, const int* in_sizes, int n_in,
                              void* d_out, int out_size, void* d_ws, size_t ws_size,
                              hipStream_t stream) {
    const float* x    = (const float*)d_in[0];
    const float* W    = (const float*)d_in[1];
    const float* U    = (const float*)d_in[2];
    const float* bv   = (const float*)d_in[3];
    const float* Wd   = (const float*)d_in[4];
    const float* bd   = (const float*)d_in[5];
    float* out = (float*)d_out;

    dim3 grid(BATCH / NB);    // 256 blocks -> 1 per CU
    dim3 block(256);          // 4 waves, one per SIMD
    gru_ring<<<grid, block, 0, stream>>>(x, W, U, bv, Wd, bd, out);
}